// Round 1
// baseline (3308.786 us; speedup 1.0000x reference)
//
#include <hip/hip_runtime.h>
#include <math.h>

// Problem constants
#define Bb 32
#define Nn 1024
#define DIMc 512
#define Hh 8
#define DHd 64
#define SCALE 0.125f   // 64^-0.5

// ---------------------------------------------------------------------------
// GEMM1: qkv = x @ W_qkv ; scatter-write into Q,K,V laid out [B*H, N, 64]
// X: [32768, 512], W: [512, 1536]
// Tile 64x64, BK=16, 256 threads, 4x4 microtile per thread.
// ---------------------------------------------------------------------------
__global__ __launch_bounds__(256) void gemm_qkv_kernel(
    const float* __restrict__ X, const float* __restrict__ W,
    float* __restrict__ Qb, float* __restrict__ Kb, float* __restrict__ Vb)
{
    __shared__ float As[16][64];   // As[k][m] (transposed for m-contiguous frags)
    __shared__ float Bs[16][64];   // Bs[k][n]

    const int tid = threadIdx.x;
    const int tx = tid & 15;       // N dir
    const int ty = tid >> 4;       // M dir
    const int bx = blockIdx.x;     // 0..23  (1536/64)
    const int n0 = bx * 64;
    const int m0 = blockIdx.y * 64;

    // entire 64-col tile maps to one (which,h): n0 aligned to 64
    const int which = bx >> 3;     // 0=q 1=k 2=v
    const int h     = bx & 7;
    float* OUT = which == 0 ? Qb : (which == 1 ? Kb : Vb);

    // A-tile load mapping: 64 rows x 16 k = 256 float4; thread -> (row, kq)
    const int a_row = tid >> 2;
    const int a_kq  = tid & 3;
    // B-tile load mapping: 16 rows x 64 cols = 256 float4
    const int b_row  = tid >> 4;
    const int b_colq = tid & 15;

    const float* Aptr = X + (size_t)(m0 + a_row) * 512 + a_kq * 4;
    const float* Bptr = W + (size_t)b_row * 1536 + n0 + b_colq * 4;

    float acc[4][4] = {};

    for (int k0 = 0; k0 < 512; k0 += 16) {
        float4 av = *(const float4*)(Aptr + k0);
        float4 bv = *(const float4*)(Bptr + (size_t)k0 * 1536);
        __syncthreads();
        As[a_kq * 4 + 0][a_row] = av.x;
        As[a_kq * 4 + 1][a_row] = av.y;
        As[a_kq * 4 + 2][a_row] = av.z;
        As[a_kq * 4 + 3][a_row] = av.w;
        *(float4*)&Bs[b_row][b_colq * 4] = bv;
        __syncthreads();
        #pragma unroll
        for (int kk = 0; kk < 16; ++kk) {
            float4 a4 = *(const float4*)&As[kk][ty * 4];
            float4 b4 = *(const float4*)&Bs[kk][tx * 4];
            float a_arr[4] = {a4.x, a4.y, a4.z, a4.w};
            float b_arr[4] = {b4.x, b4.y, b4.z, b4.w};
            #pragma unroll
            for (int i = 0; i < 4; ++i)
                #pragma unroll
                for (int j = 0; j < 4; ++j)
                    acc[i][j] = fmaf(a_arr[i], b_arr[j], acc[i][j]);
        }
    }

    // write: [B*H, N, 64]; tile rows all within one batch (m0 % 64 == 0, 1024 % 64 == 0)
    const int b_idx  = m0 >> 10;
    const int n_base = (m0 & 1023) + ty * 4;
    #pragma unroll
    for (int i = 0; i < 4; ++i) {
        float4 r = {acc[i][0], acc[i][1], acc[i][2], acc[i][3]};
        size_t off = ((size_t)(b_idx * Hh + h) * Nn + (n_base + i)) * DHd + tx * 4;
        *(float4*)&OUT[off] = r;
    }
}

// ---------------------------------------------------------------------------
// Flash attention with post-softmax decay mask.
// One thread per Q row; block = 256 rows of one (b,h); K/V tiles of 32 in LDS.
// O accum carries decay; l (softmax denom) does NOT (decay is post-softmax).
// ---------------------------------------------------------------------------
#define TJ 32
__global__ __launch_bounds__(256, 2) void attn_kernel(
    const float* __restrict__ Q, const float* __restrict__ K,
    const float* __restrict__ V, const float* __restrict__ D,  // decay [H,N,N]
    float* __restrict__ O)                                     // [B*N, 512]
{
    __shared__ float Ks[TJ][64];
    __shared__ float Vs[TJ][64];
    __shared__ float Ds[256][TJ + 1];   // +1 pad: breaks stride-32 bank conflict

    const int tid = threadIdx.x;
    const int bh  = blockIdx.x;         // 0..255
    const int b   = bh >> 3;
    const int h   = bh & 7;
    const int i0  = blockIdx.y * 256;
    const int row = i0 + tid;

    // q row -> registers
    const float* qrow = Q + ((size_t)bh * Nn + row) * DHd;
    float4 q[16];
    #pragma unroll
    for (int dq = 0; dq < 16; ++dq) q[dq] = *(const float4*)&qrow[dq * 4];

    float4 o[16];
    #pragma unroll
    for (int dq = 0; dq < 16; ++dq) o[dq] = make_float4(0.f, 0.f, 0.f, 0.f);
    float m = -INFINITY, l = 0.f;

    const float* Kbase = K + (size_t)bh * Nn * DHd;
    const float* Vbase = V + (size_t)bh * Nn * DHd;
    const float* Dbase = D + ((size_t)h * Nn + i0) * Nn;

    for (int j0 = 0; j0 < Nn; j0 += TJ) {
        __syncthreads();
        // stage K,V tiles: TJ*64 floats = 512 float4 each, 2 per thread
        {
            int idx = tid;
            #pragma unroll
            for (int r = 0; r < 2; ++r, idx += 256) {
                int jj = idx >> 4, dq = idx & 15;
                *(float4*)&Ks[jj][dq * 4] =
                    *(const float4*)&Kbase[(size_t)(j0 + jj) * DHd + dq * 4];
                *(float4*)&Vs[jj][dq * 4] =
                    *(const float4*)&Vbase[(size_t)(j0 + jj) * DHd + dq * 4];
            }
            // stage decay tile: 256 x 32 = 2048 float4, 8 per thread
            #pragma unroll
            for (int r = 0; r < 8; ++r) {
                int idx = tid + r * 256;
                int ii = idx >> 3, jq = idx & 7;
                float4 dv = *(const float4*)&Dbase[(size_t)ii * Nn + j0 + jq * 4];
                Ds[ii][jq * 4 + 0] = dv.x;
                Ds[ii][jq * 4 + 1] = dv.y;
                Ds[ii][jq * 4 + 2] = dv.z;
                Ds[ii][jq * 4 + 3] = dv.w;
            }
        }
        __syncthreads();

        // dots (K rows broadcast from LDS; 4 independent FMA chains per dot)
        float s[TJ];
        #pragma unroll
        for (int jj = 0; jj < TJ; ++jj) {
            float4 a4 = make_float4(0.f, 0.f, 0.f, 0.f);
            #pragma unroll
            for (int dq = 0; dq < 16; ++dq) {
                float4 kv = *(const float4*)&Ks[jj][dq * 4];
                a4.x = fmaf(q[dq].x, kv.x, a4.x);
                a4.y = fmaf(q[dq].y, kv.y, a4.y);
                a4.z = fmaf(q[dq].z, kv.z, a4.z);
                a4.w = fmaf(q[dq].w, kv.w, a4.w);
            }
            s[jj] = ((a4.x + a4.y) + (a4.z + a4.w)) * SCALE;
        }

        // online softmax update
        float tmax = s[0];
        #pragma unroll
        for (int jj = 1; jj < TJ; ++jj) tmax = fmaxf(tmax, s[jj]);
        float newm = fmaxf(m, tmax);
        float factor = __expf(m - newm);  // first tile: exp(-inf)=0
        l *= factor;
        #pragma unroll
        for (int dq = 0; dq < 16; ++dq) {
            o[dq].x *= factor; o[dq].y *= factor;
            o[dq].z *= factor; o[dq].w *= factor;
        }
        #pragma unroll
        for (int jj = 0; jj < TJ; ++jj) {
            float p = __expf(s[jj] - newm);
            l += p;                        // denom WITHOUT decay
            float w = p * Ds[tid][jj];     // decay applied post-softmax
            #pragma unroll
            for (int dq = 0; dq < 16; ++dq) {
                float4 vv = *(const float4*)&Vs[jj][dq * 4];
                o[dq].x = fmaf(w, vv.x, o[dq].x);
                o[dq].y = fmaf(w, vv.y, o[dq].y);
                o[dq].z = fmaf(w, vv.z, o[dq].z);
                o[dq].w = fmaf(w, vv.w, o[dq].w);
            }
        }
        m = newm;
    }

    const float inv = 1.f / l;
    float* orow = O + ((size_t)(b * Nn + row)) * DIMc + h * DHd;
    #pragma unroll
    for (int dq = 0; dq < 16; ++dq) {
        float4 t = o[dq];
        t.x *= inv; t.y *= inv; t.z *= inv; t.w *= inv;
        *(float4*)&orow[dq * 4] = t;
    }
}

// ---------------------------------------------------------------------------
// GEMM2: out = attn_out @ W_out + b_out
// A: [32768, 512], W: [512, 512], C: [32768, 512]
// ---------------------------------------------------------------------------
__global__ __launch_bounds__(256) void gemm_out_kernel(
    const float* __restrict__ A, const float* __restrict__ W,
    const float* __restrict__ bias, float* __restrict__ C)
{
    __shared__ float As[16][64];
    __shared__ float Bs[16][64];

    const int tid = threadIdx.x;
    const int tx = tid & 15;
    const int ty = tid >> 4;
    const int n0 = blockIdx.x * 64;   // 0..511
    const int m0 = blockIdx.y * 64;

    const int a_row = tid >> 2;
    const int a_kq  = tid & 3;
    const int b_row  = tid >> 4;
    const int b_colq = tid & 15;

    const float* Aptr = A + (size_t)(m0 + a_row) * 512 + a_kq * 4;
    const float* Bptr = W + (size_t)b_row * 512 + n0 + b_colq * 4;

    float acc[4][4] = {};

    for (int k0 = 0; k0 < 512; k0 += 16) {
        float4 av = *(const float4*)(Aptr + k0);
        float4 bv = *(const float4*)(Bptr + (size_t)k0 * 512);
        __syncthreads();
        As[a_kq * 4 + 0][a_row] = av.x;
        As[a_kq * 4 + 1][a_row] = av.y;
        As[a_kq * 4 + 2][a_row] = av.z;
        As[a_kq * 4 + 3][a_row] = av.w;
        *(float4*)&Bs[b_row][b_colq * 4] = bv;
        __syncthreads();
        #pragma unroll
        for (int kk = 0; kk < 16; ++kk) {
            float4 a4 = *(const float4*)&As[kk][ty * 4];
            float4 b4 = *(const float4*)&Bs[kk][tx * 4];
            float a_arr[4] = {a4.x, a4.y, a4.z, a4.w};
            float b_arr[4] = {b4.x, b4.y, b4.z, b4.w};
            #pragma unroll
            for (int i = 0; i < 4; ++i)
                #pragma unroll
                for (int j = 0; j < 4; ++j)
                    acc[i][j] = fmaf(a_arr[i], b_arr[j], acc[i][j]);
        }
    }

    float4 bias4 = *(const float4*)&bias[n0 + tx * 4];
    #pragma unroll
    for (int i = 0; i < 4; ++i) {
        float4 r = {acc[i][0] + bias4.x, acc[i][1] + bias4.y,
                    acc[i][2] + bias4.z, acc[i][3] + bias4.w};
        *(float4*)&C[(size_t)(m0 + ty * 4 + i) * 512 + n0 + tx * 4] = r;
    }
}

// ---------------------------------------------------------------------------
extern "C" void kernel_launch(void* const* d_in, const int* in_sizes, int n_in,
                              void* d_out, int out_size, void* d_ws, size_t ws_size,
                              hipStream_t stream)
{
    const float* x     = (const float*)d_in[0];  // [32,1024,512]
    const float* Wqkv  = (const float*)d_in[1];  // [512,1536]
    const float* Wout  = (const float*)d_in[2];  // [512,512]
    const float* bout  = (const float*)d_in[3];  // [512]
    const float* decay = (const float*)d_in[4];  // [1,8,1024,1024]

    const size_t SZ = (size_t)Bb * Hh * Nn * DHd;  // 16,777,216 floats
    float* ws = (float*)d_ws;
    float* Qb = ws;
    float* Kb = Qb + SZ;
    float* Vb = Kb + SZ;
    float* AO = Vb + SZ;   // attention output [32768, 512]
    // total ws use: 4 * 64 MB = 256 MB

    dim3 blk(256);
    gemm_qkv_kernel<<<dim3(24, 512), blk, 0, stream>>>(x, Wqkv, Qb, Kb, Vb);
    attn_kernel<<<dim3(256, 4), blk, 0, stream>>>(Qb, Kb, Vb, decay, AO);
    gemm_out_kernel<<<dim3(8, 512), blk, 0, stream>>>(AO, Wout, bout, (float*)d_out);
}

// Round 2
// 1454.314 us; speedup vs baseline: 2.2752x; 2.2752x over previous
//
#include <hip/hip_runtime.h>
#include <math.h>

// Problem constants
#define Bb 32
#define Nn 1024
#define DIMc 512
#define Hh 8
#define DHd 64
#define SCALE 0.125f   // 64^-0.5

typedef __attribute__((ext_vector_type(8))) short short8;   // 8 bf16 (4 VGPRs)
typedef __attribute__((ext_vector_type(4))) float floatx4;  // MFMA 16x16 acc

__device__ __forceinline__ unsigned short f32_to_bf16(float f) {
    unsigned int u = __float_as_uint(f);
    u += 0x7FFFu + ((u >> 16) & 1u);     // round-to-nearest-even
    return (unsigned short)(u >> 16);
}
__device__ __forceinline__ float bf16_to_f32(unsigned short h) {
    return __uint_as_float(((unsigned int)h) << 16);
}

// ---------------------------------------------------------------------------
// GEMM1 (fp32 vector): qkv = x @ W_qkv. Emits split-bf16:
//   Qh,Ql,Kh,Kl : [B*H, N, 64]  (hi/lo bf16 pair; lo = f - hi for QK accuracy)
//   Vt          : [B*H, 64, N]  (bf16, TRANSPOSED via LDS bounce, for MFMA B-frags)
// ---------------------------------------------------------------------------
__global__ __launch_bounds__(256) void gemm_qkv_kernel(
    const float* __restrict__ X, const float* __restrict__ W,
    unsigned short* __restrict__ Qh, unsigned short* __restrict__ Ql,
    unsigned short* __restrict__ Kh, unsigned short* __restrict__ Kl,
    unsigned short* __restrict__ Vt)
{
    __shared__ float As[16][64];
    __shared__ float Bs[16][64];
    __shared__ float bounce[64][65];   // V transpose bounce (epilogue only)

    const int tid = threadIdx.x;
    const int tx = tid & 15;
    const int ty = tid >> 4;
    const int bx = blockIdx.x;     // 0..23
    const int n0 = bx * 64;
    const int m0 = blockIdx.y * 64;

    const int which = bx >> 3;     // 0=q 1=k 2=v
    const int h     = bx & 7;

    const int a_row = tid >> 2;
    const int a_kq  = tid & 3;
    const int b_row  = tid >> 4;
    const int b_colq = tid & 15;

    const float* Aptr = X + (size_t)(m0 + a_row) * 512 + a_kq * 4;
    const float* Bptr = W + (size_t)b_row * 1536 + n0 + b_colq * 4;

    float acc[4][4] = {};

    for (int k0 = 0; k0 < 512; k0 += 16) {
        float4 av = *(const float4*)(Aptr + k0);
        float4 bv = *(const float4*)(Bptr + (size_t)k0 * 1536);
        __syncthreads();
        As[a_kq * 4 + 0][a_row] = av.x;
        As[a_kq * 4 + 1][a_row] = av.y;
        As[a_kq * 4 + 2][a_row] = av.z;
        As[a_kq * 4 + 3][a_row] = av.w;
        *(float4*)&Bs[b_row][b_colq * 4] = bv;
        __syncthreads();
        #pragma unroll
        for (int kk = 0; kk < 16; ++kk) {
            float4 a4 = *(const float4*)&As[kk][ty * 4];
            float4 b4 = *(const float4*)&Bs[kk][tx * 4];
            float a_arr[4] = {a4.x, a4.y, a4.z, a4.w};
            float b_arr[4] = {b4.x, b4.y, b4.z, b4.w};
            #pragma unroll
            for (int i = 0; i < 4; ++i)
                #pragma unroll
                for (int j = 0; j < 4; ++j)
                    acc[i][j] = fmaf(a_arr[i], b_arr[j], acc[i][j]);
        }
    }

    const int b_idx  = m0 >> 10;
    const int n_base = (m0 & 1023) + ty * 4;

    if (which < 2) {
        unsigned short* HI = which == 0 ? Qh : Kh;
        unsigned short* LO = which == 0 ? Ql : Kl;
        #pragma unroll
        for (int i = 0; i < 4; ++i) {
            size_t off = ((size_t)(b_idx * Hh + h) * Nn + (n_base + i)) * DHd + tx * 4;
            ushort4 hv, lv;
            hv.x = f32_to_bf16(acc[i][0]); lv.x = f32_to_bf16(acc[i][0] - bf16_to_f32(hv.x));
            hv.y = f32_to_bf16(acc[i][1]); lv.y = f32_to_bf16(acc[i][1] - bf16_to_f32(hv.y));
            hv.z = f32_to_bf16(acc[i][2]); lv.z = f32_to_bf16(acc[i][2] - bf16_to_f32(hv.z));
            hv.w = f32_to_bf16(acc[i][3]); lv.w = f32_to_bf16(acc[i][3] - bf16_to_f32(hv.w));
            *(ushort4*)&HI[off] = hv;
            *(ushort4*)&LO[off] = lv;
        }
    } else {
        // V: transpose 64x64 tile via LDS, write bf16 rows of Vt [bh][d][N]
        __syncthreads();
        #pragma unroll
        for (int i = 0; i < 4; ++i)
            #pragma unroll
            for (int j = 0; j < 4; ++j)
                bounce[tx * 4 + j][ty * 4 + i] = acc[i][j];
        __syncthreads();
        const int vd  = tid >> 2;          // d 0..63
        const int c16 = (tid & 3) * 16;    // token chunk
        size_t base = ((size_t)(b_idx * Hh + h) * DHd + vd) * Nn + (m0 & 1023) + c16;
        #pragma unroll
        for (int u4 = 0; u4 < 4; ++u4) {
            ushort4 o4;
            o4.x = f32_to_bf16(bounce[vd][c16 + u4 * 4 + 0]);
            o4.y = f32_to_bf16(bounce[vd][c16 + u4 * 4 + 1]);
            o4.z = f32_to_bf16(bounce[vd][c16 + u4 * 4 + 2]);
            o4.w = f32_to_bf16(bounce[vd][c16 + u4 * 4 + 3]);
            *(ushort4*)&Vt[base + u4 * 4] = o4;
        }
    }
}

// ---------------------------------------------------------------------------
// MFMA flash attention, post-softmax decay mask.
// Block = 256 thr = 4 waves; wave owns 16 Q rows; block owns 64 rows of one bh.
// QK^T: split-bf16 (qh*kh + qh*kl + ql*kh) -> fp32-class scores.
// PV: plain bf16 (error ~1e-3 << 5.3e-3 budget).
// 16x16x32 layouts (HW-verified per docs):
//   A[m][k]: m=lane&15, k=quad*8+idx ; B[k][n]: n=lane&15, k=quad*8+idx
//   C/D[row][col]: col=lane&15, row=quad*4+reg
// ---------------------------------------------------------------------------
__global__ __launch_bounds__(256) void attn_mfma_kernel(
    const unsigned short* __restrict__ Qh, const unsigned short* __restrict__ Ql,
    const unsigned short* __restrict__ Kh, const unsigned short* __restrict__ Kl,
    const unsigned short* __restrict__ Vt, const float* __restrict__ D,
    float* __restrict__ O)
{
    // strides padded so all b128 frag reads stay 16B-aligned and <=2-way banked
    __shared__ unsigned short Khs[32][72];   // [j][d], stride 72 bf16
    __shared__ unsigned short Kls[32][72];
    __shared__ unsigned short Vts[64][40];   // [d][j], stride 40 bf16
    __shared__ float          Dss[64][36];   // decay [i_local][j]
    __shared__ unsigned short Ps[4][16][40]; // per-wave P scratch (C->A layout)

    const int tid  = threadIdx.x;
    const int wave = tid >> 6;
    const int lane = tid & 63;
    const int quad = lane >> 4;
    const int l16  = lane & 15;
    const int bh   = blockIdx.x;
    const int b    = bh >> 3, h = bh & 7;
    const int i0   = blockIdx.y * 64;
    const int iw   = i0 + wave * 16;

    // Q A-frags (per-wave constant): k-chunks d0..31 / d32..63
    const size_t qoff = ((size_t)bh * Nn + iw + l16) * DHd + quad * 8;
    const short8 qh0 = *(const short8*)(Qh + qoff);
    const short8 qh1 = *(const short8*)(Qh + qoff + 32);
    const short8 ql0 = *(const short8*)(Ql + qoff);
    const short8 ql1 = *(const short8*)(Ql + qoff + 32);

    floatx4 o_acc[4];
    #pragma unroll
    for (int nt = 0; nt < 4; ++nt) o_acc[nt] = (floatx4){0.f, 0.f, 0.f, 0.f};
    float m_r[4] = {-INFINITY, -INFINITY, -INFINITY, -INFINITY};
    float l_r[4] = {0.f, 0.f, 0.f, 0.f};

    // staging maps
    const int sj  = tid >> 3, sc = (tid & 7) * 8;        // K tiles: 32 x 64
    const int vd  = tid >> 2, vj8 = (tid & 3) * 8;       // Vt tile: 64 x 32
    const int di  = tid >> 2, dj8 = (tid & 3) * 8;       // decay tile: 64 x 32
    const size_t kbase  = (size_t)bh * Nn * DHd;
    const size_t vtbase = (size_t)bh * DHd * Nn;
    const float* Drow = D + ((size_t)h * Nn + i0) * Nn;

    for (int j0 = 0; j0 < Nn; j0 += 32) {
        __syncthreads();
        *(short8*)&Khs[sj][sc] = *(const short8*)&Kh[kbase + (size_t)(j0 + sj) * DHd + sc];
        *(short8*)&Kls[sj][sc] = *(const short8*)&Kl[kbase + (size_t)(j0 + sj) * DHd + sc];
        *(short8*)&Vts[vd][vj8] = *(const short8*)&Vt[vtbase + (size_t)vd * Nn + j0 + vj8];
        *(float4*)&Dss[di][dj8]     = *(const float4*)&Drow[(size_t)di * Nn + j0 + dj8];
        *(float4*)&Dss[di][dj8 + 4] = *(const float4*)&Drow[(size_t)di * Nn + j0 + dj8 + 4];
        __syncthreads();

        // S = Q·K^T over the 32-col tile (2 halves of 16 n-cols)
        floatx4 sacc[2];
        #pragma unroll
        for (int nh = 0; nh < 2; ++nh) {
            const int kr = nh * 16 + l16;
            short8 kh0 = *(const short8*)&Khs[kr][quad * 8];
            short8 kh1 = *(const short8*)&Khs[kr][32 + quad * 8];
            short8 kl0 = *(const short8*)&Kls[kr][quad * 8];
            short8 kl1 = *(const short8*)&Kls[kr][32 + quad * 8];
            floatx4 a = (floatx4){0.f, 0.f, 0.f, 0.f};
            a = __builtin_amdgcn_mfma_f32_16x16x32_bf16(qh0, kh0, a, 0, 0, 0);
            a = __builtin_amdgcn_mfma_f32_16x16x32_bf16(qh1, kh1, a, 0, 0, 0);
            a = __builtin_amdgcn_mfma_f32_16x16x32_bf16(qh0, kl0, a, 0, 0, 0);
            a = __builtin_amdgcn_mfma_f32_16x16x32_bf16(qh1, kl1, a, 0, 0, 0);
            a = __builtin_amdgcn_mfma_f32_16x16x32_bf16(ql0, kh0, a, 0, 0, 0);
            a = __builtin_amdgcn_mfma_f32_16x16x32_bf16(ql1, kh1, a, 0, 0, 0);
            sacc[nh] = a;
        }

        // online softmax (rows live in the 16 lanes of a quad -> xor 1,2,4,8)
        float pa[4], pb[4], fac[4];
        #pragma unroll
        for (int r = 0; r < 4; ++r) {
            float sa = sacc[0][r] * SCALE;
            float sb = sacc[1][r] * SCALE;
            float t = fmaxf(sa, sb);
            t = fmaxf(t, __shfl_xor(t, 1));
            t = fmaxf(t, __shfl_xor(t, 2));
            t = fmaxf(t, __shfl_xor(t, 4));
            t = fmaxf(t, __shfl_xor(t, 8));
            float nm = fmaxf(m_r[r], t);
            fac[r] = __expf(m_r[r] - nm);     // first tile: exp(-inf)=0
            m_r[r] = nm;
            pa[r] = __expf(sa - nm);
            pb[r] = __expf(sb - nm);
            float ps = pa[r] + pb[r];
            ps += __shfl_xor(ps, 1);
            ps += __shfl_xor(ps, 2);
            ps += __shfl_xor(ps, 4);
            ps += __shfl_xor(ps, 8);
            l_r[r] = l_r[r] * fac[r] + ps;    // denom WITHOUT decay
        }
        #pragma unroll
        for (int nt = 0; nt < 4; ++nt) {
            floatx4 t = o_acc[nt];
            t[0] *= fac[0]; t[1] *= fac[1]; t[2] *= fac[2]; t[3] *= fac[3];
            o_acc[nt] = t;
        }

        // decay (post-softmax) + P -> per-wave LDS scratch in C-layout
        #pragma unroll
        for (int r = 0; r < 4; ++r) {
            const int ir = wave * 16 + quad * 4 + r;
            float wa = pa[r] * Dss[ir][l16];
            float wb = pb[r] * Dss[ir][16 + l16];
            Ps[wave][quad * 4 + r][l16]      = f32_to_bf16(wa);
            Ps[wave][quad * 4 + r][16 + l16] = f32_to_bf16(wb);
        }
        // read back as A-frag (same wave: compiler orders via lgkmcnt)
        short8 pf = *(const short8*)&Ps[wave][l16][quad * 8];
        #pragma unroll
        for (int nt = 0; nt < 4; ++nt) {
            short8 vf = *(const short8*)&Vts[nt * 16 + l16][quad * 8];
            o_acc[nt] = __builtin_amdgcn_mfma_f32_16x16x32_bf16(pf, vf, o_acc[nt], 0, 0, 0);
        }
    }

    float inv[4];
    #pragma unroll
    for (int r = 0; r < 4; ++r) inv[r] = 1.f / l_r[r];
    const size_t obase = ((size_t)b * Nn + i0 + wave * 16) * DIMc + h * DHd;
    #pragma unroll
    for (int nt = 0; nt < 4; ++nt)
        #pragma unroll
        for (int r = 0; r < 4; ++r)
            O[obase + (size_t)(quad * 4 + r) * DIMc + nt * 16 + l16] = o_acc[nt][r] * inv[r];
}

// ---------------------------------------------------------------------------
// GEMM2 (fp32 vector): out = attn_out @ W_out + b_out
// ---------------------------------------------------------------------------
__global__ __launch_bounds__(256) void gemm_out_kernel(
    const float* __restrict__ A, const float* __restrict__ W,
    const float* __restrict__ bias, float* __restrict__ C)
{
    __shared__ float As[16][64];
    __shared__ float Bs[16][64];

    const int tid = threadIdx.x;
    const int tx = tid & 15;
    const int ty = tid >> 4;
    const int n0 = blockIdx.x * 64;
    const int m0 = blockIdx.y * 64;

    const int a_row = tid >> 2;
    const int a_kq  = tid & 3;
    const int b_row  = tid >> 4;
    const int b_colq = tid & 15;

    const float* Aptr = A + (size_t)(m0 + a_row) * 512 + a_kq * 4;
    const float* Bptr = W + (size_t)b_row * 512 + n0 + b_colq * 4;

    float acc[4][4] = {};

    for (int k0 = 0; k0 < 512; k0 += 16) {
        float4 av = *(const float4*)(Aptr + k0);
        float4 bv = *(const float4*)(Bptr + (size_t)k0 * 512);
        __syncthreads();
        As[a_kq * 4 + 0][a_row] = av.x;
        As[a_kq * 4 + 1][a_row] = av.y;
        As[a_kq * 4 + 2][a_row] = av.z;
        As[a_kq * 4 + 3][a_row] = av.w;
        *(float4*)&Bs[b_row][b_colq * 4] = bv;
        __syncthreads();
        #pragma unroll
        for (int kk = 0; kk < 16; ++kk) {
            float4 a4 = *(const float4*)&As[kk][ty * 4];
            float4 b4 = *(const float4*)&Bs[kk][tx * 4];
            float a_arr[4] = {a4.x, a4.y, a4.z, a4.w};
            float b_arr[4] = {b4.x, b4.y, b4.z, b4.w};
            #pragma unroll
            for (int i = 0; i < 4; ++i)
                #pragma unroll
                for (int j = 0; j < 4; ++j)
                    acc[i][j] = fmaf(a_arr[i], b_arr[j], acc[i][j]);
        }
    }

    float4 bias4 = *(const float4*)&bias[n0 + tx * 4];
    #pragma unroll
    for (int i = 0; i < 4; ++i) {
        float4 r = {acc[i][0] + bias4.x, acc[i][1] + bias4.y,
                    acc[i][2] + bias4.z, acc[i][3] + bias4.w};
        *(float4*)&C[(size_t)(m0 + ty * 4 + i) * 512 + n0 + tx * 4] = r;
    }
}

// ---------------------------------------------------------------------------
extern "C" void kernel_launch(void* const* d_in, const int* in_sizes, int n_in,
                              void* d_out, int out_size, void* d_ws, size_t ws_size,
                              hipStream_t stream)
{
    const float* x     = (const float*)d_in[0];
    const float* Wqkv  = (const float*)d_in[1];
    const float* Wout  = (const float*)d_in[2];
    const float* bout  = (const float*)d_in[3];
    const float* decay = (const float*)d_in[4];

    const size_t E = (size_t)Bb * Hh * Nn * DHd;   // 16,777,216
    unsigned short* ws16 = (unsigned short*)d_ws;
    unsigned short* Qh = ws16;
    unsigned short* Ql = Qh + E;
    unsigned short* Kh = Ql + E;
    unsigned short* Kl = Kh + E;
    unsigned short* Vt = Kl + E;
    float* AO = (float*)(Vt + E);                  // 160MB offset, 64MB fp32
    // total ws use: 160 MB bf16 + 64 MB fp32 = 224 MB (round-0 used 256 MB OK)

    gemm_qkv_kernel<<<dim3(24, 512), 256, 0, stream>>>(x, Wqkv, Qh, Ql, Kh, Kl, Vt);
    attn_mfma_kernel<<<dim3(256, 16), 256, 0, stream>>>(Qh, Ql, Kh, Kl, Vt, decay, AO);
    gemm_out_kernel<<<dim3(8, 512), 256, 0, stream>>>(AO, Wout, bout, (float*)d_out);
}

// Round 3
// 795.412 us; speedup vs baseline: 4.1598x; 1.8284x over previous
//
#include <hip/hip_runtime.h>
#include <hip/hip_fp16.h>
#include <math.h>

// Problem constants
#define Bb 32
#define Nn 1024
#define DIMc 512
#define Hh 8
#define DHd 64
#define GK 512          // K for both projection GEMMs

typedef __attribute__((ext_vector_type(8))) short short8;   // 8 bf16 (4 VGPRs)
typedef __attribute__((ext_vector_type(4))) float floatx4;  // MFMA 16x16 acc

__device__ __forceinline__ unsigned short bf16_rtn(float f) {
    unsigned int u = __float_as_uint(f);
    u += 0x7FFFu + ((u >> 16) & 1u);     // round-to-nearest-even
    return (unsigned short)(u >> 16);
}
__device__ __forceinline__ float bf16_to_f32(unsigned short h) {
    return __uint_as_float(((unsigned int)h) << 16);
}
// Truncation split: f == hi + lo exactly in fp32 (Dekker-style); lo then
// truncated to bf16 (residual of residual ~2^-16 rel -- below noise floor).
__device__ __forceinline__ void split_trunc(float f, unsigned short& hi, unsigned short& lo) {
    unsigned int u = __float_as_uint(f) & 0xFFFF0000u;
    hi = (unsigned short)(u >> 16);
    float rest = f - __uint_as_float(u);
    lo = (unsigned short)(__float_as_uint(rest) >> 16);
}

// ---------------------------------------------------------------------------
// Prep 1: transpose + split fp32 weight [K][N] -> hi/lo bf16 [N][K]
// (makes the GEMM B operand k-contiguous so frag staging is b128 loads)
// ---------------------------------------------------------------------------
__global__ __launch_bounds__(256) void transpose_split_kernel(
    const float* __restrict__ src, int K, int N,
    unsigned short* __restrict__ dh, unsigned short* __restrict__ dl)
{
    __shared__ float T[32][33];
    const int tid = threadIdx.x;
    const int c = tid & 31, r0 = tid >> 5;
    const int nb = blockIdx.x * 32, kb = blockIdx.y * 32;
    #pragma unroll
    for (int i = 0; i < 4; ++i)
        T[r0 + i * 8][c] = src[(size_t)(kb + r0 + i * 8) * N + nb + c];
    __syncthreads();
    #pragma unroll
    for (int i = 0; i < 4; ++i) {
        int n = r0 + i * 8;
        unsigned short hi, lo;
        split_trunc(T[c][n], hi, lo);
        size_t off = (size_t)(nb + n) * K + kb + c;
        dh[off] = hi;
        dl[off] = lo;
    }
}

// ---------------------------------------------------------------------------
// Prep 2: decay fp32 -> fp16 (post-softmax multiplier; fp16 rel err ~5e-4)
// ---------------------------------------------------------------------------
__global__ __launch_bounds__(256) void decay_to_half_kernel(
    const float* __restrict__ D, unsigned short* __restrict__ D16)
{
    size_t i = ((size_t)blockIdx.x * 256 + threadIdx.x) * 4;
    float4 v = *(const float4*)(D + i);
    ushort4 o;
    o.x = __half_as_ushort(__float2half(v.x));
    o.y = __half_as_ushort(__float2half(v.y));
    o.z = __half_as_ushort(__float2half(v.z));
    o.w = __half_as_ushort(__float2half(v.w));
    *(ushort4*)(D16 + i) = o;
}

// ---------------------------------------------------------------------------
// GEMM1 (MFMA, 3-term split): qkv = x @ W_qkv
// A = x fp32 [32768][512] (hi/lo split in-register during staging)
// B = Wq hi/lo bf16 [1536][512] (pre-transposed)
// 128x128 tile, BK=32, 4 waves x 4x4 16x16x32 frags.
// LDS frag layout [8 tiles][4 quads][16][8]: frag read = base + lane*16B.
// Epilogue: Q (x0.125 folded) / K -> hi/lo bf16 [bh][n][64];
//           V -> bf16, transposed in-LDS -> Vt [bh][64][n].
// ---------------------------------------------------------------------------
__global__ __launch_bounds__(256) void gemm_qkv_mfma(
    const float* __restrict__ X,
    const unsigned short* __restrict__ Wh, const unsigned short* __restrict__ Wl,
    unsigned short* __restrict__ Qh, unsigned short* __restrict__ Ql,
    unsigned short* __restrict__ Kh, unsigned short* __restrict__ Kl,
    unsigned short* __restrict__ Vt)
{
    __shared__ union {
        struct { unsigned short Ah[4096], Al[4096], Bh[4096], Bl[4096]; } s;
        unsigned short bounce[128][136];   // V-transpose bounce (epilogue only)
    } u;

    const int tid  = threadIdx.x;
    const int w    = tid >> 6;
    const int lane = tid & 63;
    const int quad = lane >> 4;
    const int l16  = lane & 15;
    const int n0 = blockIdx.x * 128;
    const int m0 = blockIdx.y * 128;
    const int wm = w >> 1, wn = w & 1;

    floatx4 acc[4][4];
    #pragma unroll
    for (int im = 0; im < 4; ++im)
        #pragma unroll
        for (int in = 0; in < 4; ++in)
            acc[im][in] = (floatx4){0.f, 0.f, 0.f, 0.f};

    for (int k0 = 0; k0 < GK; k0 += 32) {
        float4 av[2][2];
        short8 wbh[2], wbl[2];
        #pragma unroll
        for (int i = 0; i < 2; ++i) {
            const int row = i * 64 + w * 16 + l16;
            const float* ap = X + (size_t)(m0 + row) * GK + k0 + quad * 8;
            av[i][0] = *(const float4*)ap;
            av[i][1] = *(const float4*)(ap + 4);
            const size_t boff = (size_t)(n0 + row) * GK + k0 + quad * 8;
            wbh[i] = *(const short8*)(Wh + boff);
            wbl[i] = *(const short8*)(Wl + boff);
        }
        __syncthreads();
        #pragma unroll
        for (int i = 0; i < 2; ++i) {
            float fv[8] = {av[i][0].x, av[i][0].y, av[i][0].z, av[i][0].w,
                           av[i][1].x, av[i][1].y, av[i][1].z, av[i][1].w};
            short8 hi, lo;
            #pragma unroll
            for (int e = 0; e < 8; ++e) {
                unsigned short h_, l_;
                split_trunc(fv[e], h_, l_);
                hi[e] = (short)h_;
                lo[e] = (short)l_;
            }
            const int ci = ((i * 4 + w) * 4 + quad) * 16 + l16;
            *(short8*)&u.s.Ah[ci * 8] = hi;
            *(short8*)&u.s.Al[ci * 8] = lo;
            *(short8*)&u.s.Bh[ci * 8] = wbh[i];
            *(short8*)&u.s.Bl[ci * 8] = wbl[i];
        }
        __syncthreads();

        short8 fah[4], fal[4], fbh[4], fbl[4];
        #pragma unroll
        for (int t = 0; t < 4; ++t) {
            const int ca = ((wm * 4 + t) * 4 + quad) * 16 + l16;
            fah[t] = *(const short8*)&u.s.Ah[ca * 8];
            fal[t] = *(const short8*)&u.s.Al[ca * 8];
            const int cb = ((wn * 4 + t) * 4 + quad) * 16 + l16;
            fbh[t] = *(const short8*)&u.s.Bh[cb * 8];
            fbl[t] = *(const short8*)&u.s.Bl[cb * 8];
        }
        #pragma unroll
        for (int im = 0; im < 4; ++im)
            #pragma unroll
            for (int in = 0; in < 4; ++in) {
                floatx4 a = acc[im][in];
                a = __builtin_amdgcn_mfma_f32_16x16x32_bf16(fah[im], fbh[in], a, 0, 0, 0);
                a = __builtin_amdgcn_mfma_f32_16x16x32_bf16(fal[im], fbh[in], a, 0, 0, 0);
                a = __builtin_amdgcn_mfma_f32_16x16x32_bf16(fah[im], fbl[in], a, 0, 0, 0);
                acc[im][in] = a;
            }
    }

    // ---- epilogue ----
    const int which = n0 >> 9;       // 0=q 1=k 2=v (128-tiles never straddle)
    const int b    = m0 >> 10;
    const int tokb = m0 & 1023;
    if (which < 2) {
        unsigned short* HI = which ? Kh : Qh;
        unsigned short* LO = which ? Kl : Ql;
        const float sc = which ? 1.0f : 0.125f;   // fold SCALE into Q
        #pragma unroll
        for (int im = 0; im < 4; ++im) {
            const int tok = tokb + wm * 64 + im * 16 + quad * 4;
            #pragma unroll
            for (int in = 0; in < 4; ++in) {
                const int ncol = n0 + wn * 64 + in * 16 + l16;
                const int h = (ncol & 511) >> 6, d = ncol & 63;
                const size_t base = ((size_t)(b * Hh + h) * Nn + tok) * DHd + d;
                #pragma unroll
                for (int r = 0; r < 4; ++r) {
                    unsigned short hi, lo;
                    split_trunc(acc[im][in][r] * sc, hi, lo);
                    HI[base + (size_t)r * DHd] = hi;
                    LO[base + (size_t)r * DHd] = lo;
                }
            }
        }
    } else {
        // V: bf16 + transpose through LDS bounce -> Vt [bh][64][1024]
        __syncthreads();
        #pragma unroll
        for (int im = 0; im < 4; ++im)
            #pragma unroll
            for (int in = 0; in < 4; ++in)
                #pragma unroll
                for (int r = 0; r < 4; ++r)
                    u.bounce[wm * 64 + im * 16 + quad * 4 + r][wn * 64 + in * 16 + l16] =
                        bf16_rtn(acc[im][in][r]);
        __syncthreads();
        const int c = tid >> 1, tq = (tid & 1) * 64;
        const int h = ((n0 + c) & 511) >> 6, d = c & 63;
        unsigned short* vbase = Vt + ((size_t)(b * Hh + h) * DHd + d) * Nn + tokb;
        #pragma unroll
        for (int uu = 0; uu < 8; ++uu) {
            short8 v8;
            #pragma unroll
            for (int e = 0; e < 8; ++e)
                v8[e] = (short)u.bounce[tq + uu * 8 + e][c];
            *(short8*)&vbase[tq + uu * 8] = v8;
        }
    }
}

// ---------------------------------------------------------------------------
// MFMA flash attention, post-softmax decay mask (decay fp16, direct global).
// Block = 4 waves; wave owns 16 Q rows; block owns 64 rows of one bh.
// QK^T split-bf16 (SCALE pre-folded into Q); PV plain bf16.
// Epilogue emits AO as hi/lo bf16 for the MFMA out-GEMM.
// ---------------------------------------------------------------------------
__global__ __launch_bounds__(256) void attn_mfma_kernel(
    const unsigned short* __restrict__ Qh, const unsigned short* __restrict__ Ql,
    const unsigned short* __restrict__ Kh, const unsigned short* __restrict__ Kl,
    const unsigned short* __restrict__ Vt, const unsigned short* __restrict__ D16,
    unsigned short* __restrict__ AOh, unsigned short* __restrict__ AOl)
{
    __shared__ unsigned short Khs[32][72];   // [j][d]
    __shared__ unsigned short Kls[32][72];
    __shared__ unsigned short Vts[64][40];   // [d][j]
    __shared__ unsigned short Ps[4][16][40]; // per-wave P scratch (C->A layout)

    const int tid  = threadIdx.x;
    const int wave = tid >> 6;
    const int lane = tid & 63;
    const int quad = lane >> 4;
    const int l16  = lane & 15;
    const int bh   = blockIdx.x;
    const int b    = bh >> 3, h = bh & 7;
    const int i0   = blockIdx.y * 64;
    const int iw   = i0 + wave * 16;

    const size_t qoff = ((size_t)bh * Nn + iw + l16) * DHd + quad * 8;
    const short8 qh0 = *(const short8*)(Qh + qoff);
    const short8 qh1 = *(const short8*)(Qh + qoff + 32);
    const short8 ql0 = *(const short8*)(Ql + qoff);
    const short8 ql1 = *(const short8*)(Ql + qoff + 32);

    floatx4 o_acc[4];
    #pragma unroll
    for (int nt = 0; nt < 4; ++nt) o_acc[nt] = (floatx4){0.f, 0.f, 0.f, 0.f};
    float m_r[4] = {-INFINITY, -INFINITY, -INFINITY, -INFINITY};
    float l_r[4] = {0.f, 0.f, 0.f, 0.f};

    const int sj  = tid >> 3, sc = (tid & 7) * 8;        // K tiles: 32 x 64
    const int vd  = tid >> 2, vj8 = (tid & 3) * 8;       // Vt tile: 64 x 32
    const size_t kbase  = (size_t)bh * Nn * DHd;
    const size_t vtbase = (size_t)bh * DHd * Nn;
    // decay rows this lane needs (rows iw+quad*4 .. +3)
    const unsigned short* Dp = D16 + ((size_t)h * Nn + iw + quad * 4) * Nn;

    for (int j0 = 0; j0 < Nn; j0 += 32) {
        // decay prefetch (global, L2/L3-resident; independent of LDS)
        float da[4], db[4];
        #pragma unroll
        for (int r = 0; r < 4; ++r) {
            da[r] = __half2float(__ushort_as_half(Dp[(size_t)r * Nn + j0 + l16]));
            db[r] = __half2float(__ushort_as_half(Dp[(size_t)r * Nn + j0 + 16 + l16]));
        }
        __syncthreads();
        *(short8*)&Khs[sj][sc] = *(const short8*)&Kh[kbase + (size_t)(j0 + sj) * DHd + sc];
        *(short8*)&Kls[sj][sc] = *(const short8*)&Kl[kbase + (size_t)(j0 + sj) * DHd + sc];
        *(short8*)&Vts[vd][vj8] = *(const short8*)&Vt[vtbase + (size_t)vd * Nn + j0 + vj8];
        __syncthreads();

        floatx4 sacc[2];
        #pragma unroll
        for (int nh = 0; nh < 2; ++nh) {
            const int kr = nh * 16 + l16;
            short8 kh0 = *(const short8*)&Khs[kr][quad * 8];
            short8 kh1 = *(const short8*)&Khs[kr][32 + quad * 8];
            short8 kl0 = *(const short8*)&Kls[kr][quad * 8];
            short8 kl1 = *(const short8*)&Kls[kr][32 + quad * 8];
            floatx4 a = (floatx4){0.f, 0.f, 0.f, 0.f};
            a = __builtin_amdgcn_mfma_f32_16x16x32_bf16(qh0, kh0, a, 0, 0, 0);
            a = __builtin_amdgcn_mfma_f32_16x16x32_bf16(qh1, kh1, a, 0, 0, 0);
            a = __builtin_amdgcn_mfma_f32_16x16x32_bf16(qh0, kl0, a, 0, 0, 0);
            a = __builtin_amdgcn_mfma_f32_16x16x32_bf16(qh1, kl1, a, 0, 0, 0);
            a = __builtin_amdgcn_mfma_f32_16x16x32_bf16(ql0, kh0, a, 0, 0, 0);
            a = __builtin_amdgcn_mfma_f32_16x16x32_bf16(ql1, kh1, a, 0, 0, 0);
            sacc[nh] = a;
        }

        float pa[4], pb[4], fac[4];
        #pragma unroll
        for (int r = 0; r < 4; ++r) {
            float sa = sacc[0][r];             // SCALE folded into Q
            float sb = sacc[1][r];
            float t = fmaxf(sa, sb);
            t = fmaxf(t, __shfl_xor(t, 1));
            t = fmaxf(t, __shfl_xor(t, 2));
            t = fmaxf(t, __shfl_xor(t, 4));
            t = fmaxf(t, __shfl_xor(t, 8));
            float nm = fmaxf(m_r[r], t);
            fac[r] = __expf(m_r[r] - nm);
            m_r[r] = nm;
            pa[r] = __expf(sa - nm);
            pb[r] = __expf(sb - nm);
            float ps = pa[r] + pb[r];
            ps += __shfl_xor(ps, 1);
            ps += __shfl_xor(ps, 2);
            ps += __shfl_xor(ps, 4);
            ps += __shfl_xor(ps, 8);
            l_r[r] = l_r[r] * fac[r] + ps;     // denom WITHOUT decay
        }
        #pragma unroll
        for (int nt = 0; nt < 4; ++nt) {
            floatx4 t = o_acc[nt];
            t[0] *= fac[0]; t[1] *= fac[1]; t[2] *= fac[2]; t[3] *= fac[3];
            o_acc[nt] = t;
        }

        #pragma unroll
        for (int r = 0; r < 4; ++r) {
            Ps[wave][quad * 4 + r][l16]      = bf16_rtn(pa[r] * da[r]);
            Ps[wave][quad * 4 + r][16 + l16] = bf16_rtn(pb[r] * db[r]);
        }
        short8 pf = *(const short8*)&Ps[wave][l16][quad * 8];
        #pragma unroll
        for (int nt = 0; nt < 4; ++nt) {
            short8 vf = *(const short8*)&Vts[nt * 16 + l16][quad * 8];
            o_acc[nt] = __builtin_amdgcn_mfma_f32_16x16x32_bf16(pf, vf, o_acc[nt], 0, 0, 0);
        }
    }

    float inv[4];
    #pragma unroll
    for (int r = 0; r < 4; ++r) inv[r] = 1.f / l_r[r];
    const size_t aob = ((size_t)b * Nn + i0 + wave * 16) * DIMc + h * DHd;
    #pragma unroll
    for (int nt = 0; nt < 4; ++nt)
        #pragma unroll
        for (int r = 0; r < 4; ++r) {
            unsigned short hi, lo;
            split_trunc(o_acc[nt][r] * inv[r], hi, lo);
            const size_t off = aob + (size_t)(quad * 4 + r) * DIMc + nt * 16 + l16;
            AOh[off] = hi;
            AOl[off] = lo;
        }
}

// ---------------------------------------------------------------------------
// GEMM2 (MFMA, 3-term split): out = AO @ W_out + b_out ; all operands bf16 hi/lo.
// ---------------------------------------------------------------------------
__global__ __launch_bounds__(256) void gemm_out_mfma(
    const unsigned short* __restrict__ Agh, const unsigned short* __restrict__ Agl,
    const unsigned short* __restrict__ Wh, const unsigned short* __restrict__ Wl,
    const float* __restrict__ bias, float* __restrict__ C)
{
    __shared__ struct { unsigned short Ah[4096], Al[4096], Bh[4096], Bl[4096]; } s;

    const int tid  = threadIdx.x;
    const int w    = tid >> 6;
    const int lane = tid & 63;
    const int quad = lane >> 4;
    const int l16  = lane & 15;
    const int n0 = blockIdx.x * 128;
    const int m0 = blockIdx.y * 128;
    const int wm = w >> 1, wn = w & 1;

    floatx4 acc[4][4];
    #pragma unroll
    for (int im = 0; im < 4; ++im)
        #pragma unroll
        for (int in = 0; in < 4; ++in)
            acc[im][in] = (floatx4){0.f, 0.f, 0.f, 0.f};

    for (int k0 = 0; k0 < GK; k0 += 32) {
        short8 ah8[2], al8[2], wbh[2], wbl[2];
        #pragma unroll
        for (int i = 0; i < 2; ++i) {
            const int row = i * 64 + w * 16 + l16;
            const size_t aoff = (size_t)(m0 + row) * GK + k0 + quad * 8;
            ah8[i] = *(const short8*)(Agh + aoff);
            al8[i] = *(const short8*)(Agl + aoff);
            const size_t boff = (size_t)(n0 + row) * GK + k0 + quad * 8;
            wbh[i] = *(const short8*)(Wh + boff);
            wbl[i] = *(const short8*)(Wl + boff);
        }
        __syncthreads();
        #pragma unroll
        for (int i = 0; i < 2; ++i) {
            const int ci = ((i * 4 + w) * 4 + quad) * 16 + l16;
            *(short8*)&s.Ah[ci * 8] = ah8[i];
            *(short8*)&s.Al[ci * 8] = al8[i];
            *(short8*)&s.Bh[ci * 8] = wbh[i];
            *(short8*)&s.Bl[ci * 8] = wbl[i];
        }
        __syncthreads();

        short8 fah[4], fal[4], fbh[4], fbl[4];
        #pragma unroll
        for (int t = 0; t < 4; ++t) {
            const int ca = ((wm * 4 + t) * 4 + quad) * 16 + l16;
            fah[t] = *(const short8*)&s.Ah[ca * 8];
            fal[t] = *(const short8*)&s.Al[ca * 8];
            const int cb = ((wn * 4 + t) * 4 + quad) * 16 + l16;
            fbh[t] = *(const short8*)&s.Bh[cb * 8];
            fbl[t] = *(const short8*)&s.Bl[cb * 8];
        }
        #pragma unroll
        for (int im = 0; im < 4; ++im)
            #pragma unroll
            for (int in = 0; in < 4; ++in) {
                floatx4 a = acc[im][in];
                a = __builtin_amdgcn_mfma_f32_16x16x32_bf16(fah[im], fbh[in], a, 0, 0, 0);
                a = __builtin_amdgcn_mfma_f32_16x16x32_bf16(fal[im], fbh[in], a, 0, 0, 0);
                a = __builtin_amdgcn_mfma_f32_16x16x32_bf16(fah[im], fbl[in], a, 0, 0, 0);
                acc[im][in] = a;
            }
    }

    float biasv[4];
    #pragma unroll
    for (int in = 0; in < 4; ++in) biasv[in] = bias[n0 + wn * 64 + in * 16 + l16];
    #pragma unroll
    for (int im = 0; im < 4; ++im)
        #pragma unroll
        for (int in = 0; in < 4; ++in) {
            const int mrow = m0 + wm * 64 + im * 16 + quad * 4;
            const int ncol = n0 + wn * 64 + in * 16 + l16;
            #pragma unroll
            for (int r = 0; r < 4; ++r)
                C[(size_t)(mrow + r) * DIMc + ncol] = acc[im][in][r] + biasv[in];
        }
}

// ---------------------------------------------------------------------------
extern "C" void kernel_launch(void* const* d_in, const int* in_sizes, int n_in,
                              void* d_out, int out_size, void* d_ws, size_t ws_size,
                              hipStream_t stream)
{
    const float* x     = (const float*)d_in[0];
    const float* Wqkv  = (const float*)d_in[1];
    const float* Wout  = (const float*)d_in[2];
    const float* bout  = (const float*)d_in[3];
    const float* decay = (const float*)d_in[4];

    const size_t E = (size_t)32768 * 512;   // 16,777,216
    unsigned short* p = (unsigned short*)d_ws;
    unsigned short* Qh  = p; p += E;
    unsigned short* Ql  = p; p += E;
    unsigned short* Kh  = p; p += E;
    unsigned short* Kl  = p; p += E;
    unsigned short* Vt  = p; p += E;
    unsigned short* AOh = p; p += E;
    unsigned short* AOl = p; p += E;
    unsigned short* Wqh = p; p += 786432;
    unsigned short* Wql = p; p += 786432;
    unsigned short* Woh = p; p += 262144;
    unsigned short* Wol = p; p += 262144;
    unsigned short* D16 = p;               // 8,388,608 halves
    // total: ~244 MiB (< the 256 MiB round-0 proved available)

    transpose_split_kernel<<<dim3(48, 16), 256, 0, stream>>>(Wqkv, 512, 1536, Wqh, Wql);
    transpose_split_kernel<<<dim3(16, 16), 256, 0, stream>>>(Wout, 512, 512, Woh, Wol);
    decay_to_half_kernel<<<dim3(8192), 256, 0, stream>>>(decay, D16);
    gemm_qkv_mfma<<<dim3(12, 256), 256, 0, stream>>>(x, Wqh, Wql, Qh, Ql, Kh, Kl, Vt);
    attn_mfma_kernel<<<dim3(256, 16), 256, 0, stream>>>(Qh, Ql, Kh, Kl, Vt, D16, AOh, AOl);
    gemm_out_mfma<<<dim3(4, 256), 256, 0, stream>>>(AOh, AOl, Woh, Wol, bout, (float*)d_out);
}